// Round 14
// baseline (733.220 us; speedup 1.0000x reference)
//
#include <hip/hip_runtime.h>

#define NN 50000
#define NE 800000
#define NG 512
#define HC 64
#define NL 5
#define GD_COLS 321
#define BN_EPS 1e-5f
#define DEG_CAP 64  // max degree: Poisson(16), P(>64) ~ 1e-18 — fixed-stride edge table

#define SLICE 6250   // NN/8: destination slice per XCD group
#define ECHUNK 3125  // NE/256: edge chunk per block pair-group

typedef unsigned short bf16_t;
typedef unsigned int uiv4 __attribute__((ext_vector_type(4)));
typedef __attribute__((ext_vector_type(8))) short short8v;   // 8 bf16 = 4 VGPRs (MFMA A/B frag)
typedef __attribute__((ext_vector_type(4))) float f32x4;     // MFMA C/D frag
typedef __attribute__((ext_vector_type(4))) unsigned uint4v;

static __device__ __forceinline__ unsigned f2bfbits(float f) {
    unsigned u = __float_as_uint(f);
    return (u + 0x7FFFu + ((u >> 16) & 1u)) >> 16;
}
static __device__ __forceinline__ bf16_t f2bf(float f) { return (bf16_t)f2bfbits(f); }
static __device__ __forceinline__ float bf2f(bf16_t h) {
    return __uint_as_float(((unsigned)h) << 16);
}
static __device__ __forceinline__ float bflo(unsigned w) { return __uint_as_float(w << 16); }
static __device__ __forceinline__ float bfhi(unsigned w) {
    return __uint_as_float(w & 0xffff0000u);
}

// ---------------- edge table build: XCD-sliced scatter + scratch zeroing ----------------
// Residual ~25 MB FETCH / ~30 MB WRITE matches memory-side atomic RMW (800K x 32B
// sectors); cache-policy levers proven ineffective (round 7). Near-floor.
__global__ __launch_bounds__(256) void scatter_kernel(const int* __restrict__ ei,
                                                      int* __restrict__ cnt,
                                                      unsigned short* __restrict__ ssrc,
                                                      float* __restrict__ stats,
                                                      float* __restrict__ gdesc) {
    int t = threadIdx.x;
    int g = blockIdx.x & 7;
    int c = blockIdx.x >> 3;
    int gt = blockIdx.x * 256 + t;
    int total = gridDim.x * 256;
    for (int i = gt; i < NL * 256; i += total) stats[i] = 0.f;
    for (int i = gt; i < NG * GD_COLS; i += total) gdesc[i] = 0.f;
    int lo = g * SLICE, hi = lo + SLICE;
    int e0 = c * ECHUNK;
    int e1 = e0 + ECHUNK;
    if (e1 > NE) e1 = NE;
    for (int e = e0 + t; e < e1; e += 256) {
        int d = ei[NE + e];
        if (d >= lo && d < hi) {
            int s = ei[e];
            int pos = atomicAdd(&cnt[d], 1);
            if (pos < DEG_CAP) ssrc[(d << 6) + pos] = (unsigned short)s;
        }
    }
}

// ---------------- layer 0: gather0 + rank-1 expand + stats0 + first_desc ----------------
__global__ __launch_bounds__(256) void layer0_kernel(
    const float* __restrict__ x, const int* __restrict__ cnt,
    const unsigned short* __restrict__ ssrc, const float* __restrict__ w,
    const float* __restrict__ bias, const int* __restrict__ batch, float* __restrict__ gdesc,
    bf16_t* __restrict__ y, float* __restrict__ stats) {
    __shared__ float z0p[256];
    __shared__ float z0s[64];
    int t = threadIdx.x, lane = t & 63, wid = t >> 6;
    int r0 = blockIdx.x * 64;
    if (t < 64) {
        int i = r0 + t;
        if (i < NN) atomicAdd(&gdesc[batch[i] * GD_COLS], x[i]);
    }
    {
        int node = t >> 2, sub = t & 3;
        int i = r0 + node;
        float acc = 0.f;
        if (i < NN) {
            int deg = cnt[i];
            if (deg > DEG_CAP) deg = DEG_CAP;
            int pa = i << 6;
            for (int p = sub; p < deg; p += 4) acc += x[ssrc[pa + p]];
            if (sub == 0) acc += x[i];
        }
        z0p[t] = acc;
    }
    __syncthreads();
    if (t < 64) z0s[t] = z0p[4 * t] + z0p[4 * t + 1] + z0p[4 * t + 2] + z0p[4 * t + 3];
    __syncthreads();
    float wv = w[lane], bv = bias[lane];
    float s = 0.f, s2 = 0.f;
    for (int j = 0; j < 16; ++j) {
        int r = r0 + wid * 16 + j;
        if (r < NN) {
            float v = z0s[wid * 16 + j] * wv + bv;
            y[r * HC + lane] = f2bf(v);
            s += v;
            s2 += v * v;
        }
    }
    __shared__ float ls[256], ls2[256];
    ls[t] = s;
    ls2[t] = s2;
    __syncthreads();
    if (wid == 0) {
        float ts = ls[lane] + ls[64 + lane] + ls[128 + lane] + ls[192 + lane];
        float t2 = ls2[lane] + ls2[64 + lane] + ls2[128 + lane] + ls2[192 + lane];
        atomicAdd(&stats[lane], ts);
        atomicAdd(&stats[64 + lane], t2);
    }
}

// ---------------- K1: BN2(prev)+ReLU fused gather + gdesc(prev) + MFMA GEMM1 + stats1 ----
// 32 rows/block, 256 threads, 4 waves x 8 rows. Per-wave structure IDENTICAL to the
// proven 403µs config (8 rows/wave single pass, rv0 hoist, VGPR<=64 pinned by (256,8)).
// Finer block granularity: 1563 blocks = 6.1/CU halves the drain-tail that capped
// occupancy at ~25% with 3.05 blocks/CU (perm reorder was net-negative — round 13).
__global__ __launch_bounds__(256, 8) void gather_gemm_kernel(
    const bf16_t* __restrict__ u, const float* __restrict__ statsPrev,
    const float* __restrict__ gPrev, const float* __restrict__ bPrev,
    const int* __restrict__ cnt, const unsigned short* __restrict__ ssrc,
    const float* __restrict__ w, const float* __restrict__ bias, const int* __restrict__ batch,
    float* __restrict__ gdesc, int layerPrev, bf16_t* __restrict__ out,
    float* __restrict__ statsOut) {
    __shared__ unsigned zw[32 * 33];
    __shared__ unsigned wsm[64 * 33];
    __shared__ float a1[64], s1[64];
    __shared__ float redS[4][64], redQ[4][64];
    int t = threadIdx.x, lane = t & 63, wid = t >> 6;  // wid in [0,4)
    int r0 = blockIdx.x * 32;
    int li = lane & 7;       // channel slice owner
    int gq = lane >> 3;      // row within wave's 8
    int gbase = lane & 56;   // first lane of this 8-lane group
    int nB = r0 + wid * 8 + gq;
    uiv4 myidx = {0, 0, 0, 0};
    uiv4 selfv = {0, 0, 0, 0};
    int degB = 0;
    if (nB < NN) {
        degB = cnt[nB];
        if (degB > DEG_CAP) degB = DEG_CAP;
        myidx = *(const uiv4*)&ssrc[((size_t)nB << 6) + li * 8];
        selfv = *(const uiv4*)&u[(size_t)nB * HC + li * 8];
    }
    // --- hoisted batch-0 gather loads (masked lanes read u[0..] harmlessly) ---
    uiv4 rv0[8];
    {
        unsigned w0 = __shfl(myidx[0], gbase);
        unsigned w1 = __shfl(myidx[1], gbase);
        unsigned w2 = __shfl(myidx[2], gbase);
        unsigned w3 = __shfl(myidx[3], gbase);
        int id[8] = {(int)(w0 & 0xffff), (int)(w0 >> 16), (int)(w1 & 0xffff),
                     (int)(w1 >> 16),    (int)(w2 & 0xffff), (int)(w2 >> 16),
                     (int)(w3 & 0xffff), (int)(w3 >> 16)};
#pragma unroll
        for (int e = 0; e < 8; ++e)
            rv0[e] = *(const uiv4*)&u[(size_t)id[e] * HC + li * 8];
    }
    if (t < 64) {
        float mu = statsPrev[t] * (1.0f / NN);
        float var = statsPrev[64 + t] * (1.0f / NN) - mu * mu;
        float a = gPrev[t] * rsqrtf(var + BN_EPS);
        a1[t] = a;
        s1[t] = bPrev[t] - mu * a;
    }
    for (int idx = t; idx < 2048; idx += 256) {
        int kk = idx >> 6, c = idx & 63;
        unsigned lo = f2bfbits(w[(2 * kk) * 64 + c]);
        unsigned hi = f2bfbits(w[(2 * kk + 1) * 64 + c]);
        wsm[c * 33 + kk] = lo | (hi << 16);
    }
    __syncthreads();
    // Phase B: self-term init + edge gather (8-lane groups, shfl-broadcast indices)
    {
        float a8[8], s8[8];
#pragma unroll
        for (int c = 0; c < 8; ++c) {
            a8[c] = a1[li * 8 + c];
            s8[c] = s1[li * 8 + c];
        }
        float acc[8];
        if (nB < NN) {
            acc[0] = fmaxf(bflo(selfv[0]) * a8[0] + s8[0], 0.f);
            acc[1] = fmaxf(bfhi(selfv[0]) * a8[1] + s8[1], 0.f);
            acc[2] = fmaxf(bflo(selfv[1]) * a8[2] + s8[2], 0.f);
            acc[3] = fmaxf(bfhi(selfv[1]) * a8[3] + s8[3], 0.f);
            acc[4] = fmaxf(bflo(selfv[2]) * a8[4] + s8[4], 0.f);
            acc[5] = fmaxf(bfhi(selfv[2]) * a8[5] + s8[5], 0.f);
            acc[6] = fmaxf(bflo(selfv[3]) * a8[6] + s8[6], 0.f);
            acc[7] = fmaxf(bfhi(selfv[3]) * a8[7] + s8[7], 0.f);
        } else {
#pragma unroll
            for (int c = 0; c < 8; ++c) acc[c] = 0.f;
        }
        if (degB > 0) {
            uiv4 rv[8];
#pragma unroll
            for (int e = 0; e < 8; ++e) rv[e] = rv0[e];
            int cntA = degB < 8 ? degB : 8;
            for (int b = 1; cntA > 0; ++b) {
                uiv4 nv[8];
                int cntB = 0;
                if (b * 8 < degB) {
                    unsigned w0 = __shfl(myidx[0], gbase + b);
                    unsigned w1 = __shfl(myidx[1], gbase + b);
                    unsigned w2 = __shfl(myidx[2], gbase + b);
                    unsigned w3 = __shfl(myidx[3], gbase + b);
                    int id[8] = {(int)(w0 & 0xffff), (int)(w0 >> 16), (int)(w1 & 0xffff),
                                 (int)(w1 >> 16),    (int)(w2 & 0xffff), (int)(w2 >> 16),
                                 (int)(w3 & 0xffff), (int)(w3 >> 16)};
#pragma unroll
                    for (int e = 0; e < 8; ++e)
                        nv[e] = *(const uiv4*)&u[(size_t)id[e] * HC + li * 8];
                    cntB = degB - b * 8;
                    if (cntB > 8) cntB = 8;
                }
#pragma unroll
                for (int e = 0; e < 8; ++e) {
                    float v0 = fmaxf(bflo(rv[e][0]) * a8[0] + s8[0], 0.f);
                    float v1 = fmaxf(bfhi(rv[e][0]) * a8[1] + s8[1], 0.f);
                    float v2 = fmaxf(bflo(rv[e][1]) * a8[2] + s8[2], 0.f);
                    float v3 = fmaxf(bfhi(rv[e][1]) * a8[3] + s8[3], 0.f);
                    float v4 = fmaxf(bflo(rv[e][2]) * a8[4] + s8[4], 0.f);
                    float v5 = fmaxf(bfhi(rv[e][2]) * a8[5] + s8[5], 0.f);
                    float v6 = fmaxf(bflo(rv[e][3]) * a8[6] + s8[6], 0.f);
                    float v7 = fmaxf(bfhi(rv[e][3]) * a8[7] + s8[7], 0.f);
                    if (e < cntA) {
                        acc[0] += v0;
                        acc[1] += v1;
                        acc[2] += v2;
                        acc[3] += v3;
                        acc[4] += v4;
                        acc[5] += v5;
                        acc[6] += v6;
                        acc[7] += v7;
                    }
                }
#pragma unroll
                for (int e = 0; e < 8; ++e) rv[e] = nv[e];
                cntA = cntB;
            }
        }
        int lr = wid * 8 + gq;
        unsigned* zp = &zw[lr * 33 + li * 4];
        zp[0] = f2bfbits(acc[0]) | (f2bfbits(acc[1]) << 16);
        zp[1] = f2bfbits(acc[2]) | (f2bfbits(acc[3]) << 16);
        zp[2] = f2bfbits(acc[4]) | (f2bfbits(acc[5]) << 16);
        zp[3] = f2bfbits(acc[6]) | (f2bfbits(acc[7]) << 16);
    }
    // Phase A: gdesc segmented sum only (lane = channel), rows wid*8..wid*8+7
    {
        float av = a1[lane], sv = s1[lane];
        int col = 1 + layerPrev * HC + lane;
        float gacc = 0.f;
        int cur = -1;
        for (int j = 0; j < 8; ++j) {
            int gr = r0 + wid * 8 + j;
            if (gr < NN) {
                float hv = fmaxf(bf2f(u[(size_t)gr * HC + lane]) * av + sv, 0.f);
                int gid = batch[gr];
                if (gid != cur) {
                    if (cur >= 0) atomicAdd(&gdesc[cur * GD_COLS + col], gacc);
                    cur = gid;
                    gacc = 0.f;
                }
                gacc += hv;
            }
        }
        if (cur >= 0) atomicAdd(&gdesc[cur * GD_COLS + col], gacc);
    }
    __syncthreads();  // zw rows cross waves for MFMA A-frags
    // MFMA: 2 row-tiles x 4 col-tiles over 4 waves; wave wid -> (tr=wid>>1, tc0=(wid&1)*2)
    {
        int l15 = lane & 15, l4 = lane >> 4;
        int tr = wid >> 1;
        int tc0 = (wid & 1) * 2;
        f32x4 d0 = {0.f, 0.f, 0.f, 0.f}, d1 = {0.f, 0.f, 0.f, 0.f};
        const unsigned* arow = &zw[(tr * 16 + l15) * 33];
        const unsigned* brow0 = &wsm[(tc0 * 16 + l15) * 33];
        const unsigned* brow1 = &wsm[((tc0 + 1) * 16 + l15) * 33];
#pragma unroll
        for (int kc = 0; kc < 2; ++kc) {
            int kb = kc * 16 + l4 * 4;
            uint4v aw = {arow[kb], arow[kb + 1], arow[kb + 2], arow[kb + 3]};
            uint4v bw0 = {brow0[kb], brow0[kb + 1], brow0[kb + 2], brow0[kb + 3]};
            uint4v bw1 = {brow1[kb], brow1[kb + 1], brow1[kb + 2], brow1[kb + 3]};
            short8v af = __builtin_bit_cast(short8v, aw);
            d0 = __builtin_amdgcn_mfma_f32_16x16x32_bf16(af, __builtin_bit_cast(short8v, bw0),
                                                         d0, 0, 0, 0);
            d1 = __builtin_amdgcn_mfma_f32_16x16x32_bf16(af, __builtin_bit_cast(short8v, bw1),
                                                         d1, 0, 0, 0);
        }
        int c0 = tc0 * 16 + l15, c1 = c0 + 16;
        float bv0 = bias[c0], bv1 = bias[c1];
        float s0 = 0.f, q0 = 0.f, s1v = 0.f, q1 = 0.f;
#pragma unroll
        for (int j = 0; j < 4; ++j) {
            int gr = r0 + tr * 16 + l4 * 4 + j;
            if (gr < NN) {
                float v0 = d0[j] + bv0, v1 = d1[j] + bv1;
                out[(size_t)gr * HC + c0] = f2bf(v0);
                out[(size_t)gr * HC + c1] = f2bf(v1);
                s0 += v0;
                q0 += v0 * v0;
                s1v += v1;
                q1 += v1 * v1;
            }
        }
        s0 += __shfl_xor(s0, 16); s0 += __shfl_xor(s0, 32);
        q0 += __shfl_xor(q0, 16); q0 += __shfl_xor(q0, 32);
        s1v += __shfl_xor(s1v, 16); s1v += __shfl_xor(s1v, 32);
        q1 += __shfl_xor(q1, 16); q1 += __shfl_xor(q1, 32);
        if (l4 == 0) { redS[wid][c0] = s0; redQ[wid][c0] = q0; }
        else if (l4 == 1) { redS[wid][c1] = s1v; redQ[wid][c1] = q1; }
        else if (l4 == 2) { redS[wid][c0 ^ 32] = 0.f; redQ[wid][c0 ^ 32] = 0.f; }
        else { redS[wid][c1 ^ 32] = 0.f; redQ[wid][c1 ^ 32] = 0.f; }
    }
    __syncthreads();
    if (t < 64) {
        float ts = 0.f, t2 = 0.f;
#pragma unroll
        for (int k = 0; k < 4; ++k) {
            ts += redS[k][t];
            t2 += redQ[k][t];
        }
        atomicAdd(&statsOut[t], ts);
        atomicAdd(&statsOut[64 + t], t2);
    }
}

// ---------------- K2: BN1+ReLU staging + MFMA GEMM2 + stats2 (128 rows/block) ----------
__global__ __launch_bounds__(512) void gemm128_norm_kernel(
    const bf16_t* __restrict__ in, const float* __restrict__ w, const float* __restrict__ bias,
    const float* __restrict__ statsIn, const float* __restrict__ gIn,
    const float* __restrict__ bIn, bf16_t* __restrict__ out, float* __restrict__ statsOut) {
    __shared__ unsigned zw[128 * 33];
    __shared__ unsigned wsm[64 * 33];
    __shared__ float a1[64], s1[64];
    __shared__ float redS[8][64], redQ[8][64];
    int t = threadIdx.x, lane = t & 63, wid = t >> 6;
    int r0 = blockIdx.x * 128;
    if (t < 64) {
        float mu = statsIn[t] * (1.0f / NN);
        float var = statsIn[64 + t] * (1.0f / NN) - mu * mu;
        float a = gIn[t] * rsqrtf(var + BN_EPS);
        a1[t] = a;
        s1[t] = bIn[t] - mu * a;
    }
    for (int idx = t; idx < 2048; idx += 512) {
        int kk = idx >> 6, c = idx & 63;
        unsigned lo = f2bfbits(w[(2 * kk) * 64 + c]);
        unsigned hi = f2bfbits(w[(2 * kk + 1) * 64 + c]);
        wsm[c * 33 + kk] = lo | (hi << 16);
    }
    __syncthreads();
    for (int idx = t; idx < 1024; idx += 512) {
        int off = idx * 8;
        int r = off >> 6;
        int k = off & 63;
        uiv4 wv4 = {0u, 0u, 0u, 0u};
        int gr = r0 + r;
        if (gr < NN) wv4 = *(const uiv4*)&in[(size_t)gr * HC + k];
        unsigned* zp = &zw[r * 33 + (k >> 1)];
#pragma unroll
        for (int j = 0; j < 4; ++j) {
            unsigned word = wv4[j];
            int kk = k + 2 * j;
            float v0 = fmaxf(bflo(word) * a1[kk] + s1[kk], 0.f);
            float v1 = fmaxf(bfhi(word) * a1[kk + 1] + s1[kk + 1], 0.f);
            zp[j] = f2bfbits(v0) | (f2bfbits(v1) << 16);
        }
    }
    __syncthreads();
    int l15 = lane & 15, l4 = lane >> 4;
    const unsigned* arow = &zw[(wid * 16 + l15) * 33];
    f32x4 d[4];
#pragma unroll
    for (int tc = 0; tc < 4; ++tc) d[tc] = (f32x4){0.f, 0.f, 0.f, 0.f};
#pragma unroll
    for (int kc = 0; kc < 2; ++kc) {
        int kb = kc * 16 + l4 * 4;
        uint4v aw = {arow[kb], arow[kb + 1], arow[kb + 2], arow[kb + 3]};
        short8v af = __builtin_bit_cast(short8v, aw);
#pragma unroll
        for (int tc = 0; tc < 4; ++tc) {
            const unsigned* brow = &wsm[(tc * 16 + l15) * 33];
            uint4v bw = {brow[kb], brow[kb + 1], brow[kb + 2], brow[kb + 3]};
            d[tc] = __builtin_amdgcn_mfma_f32_16x16x32_bf16(af, __builtin_bit_cast(short8v, bw),
                                                            d[tc], 0, 0, 0);
        }
    }
    float ss[4], qq[4];
#pragma unroll
    for (int tc = 0; tc < 4; ++tc) {
        int cc = tc * 16 + l15;
        float bv = bias[cc];
        float s = 0.f, q = 0.f;
#pragma unroll
        for (int j = 0; j < 4; ++j) {
            int gr = r0 + wid * 16 + l4 * 4 + j;
            if (gr < NN) {
                float v = d[tc][j] + bv;
                out[(size_t)gr * HC + cc] = f2bf(v);
                s += v;
                q += v * v;
            }
        }
        s += __shfl_xor(s, 16); s += __shfl_xor(s, 32);
        q += __shfl_xor(q, 16); q += __shfl_xor(q, 32);
        ss[tc] = s;
        qq[tc] = q;
    }
    if (lane < 16) {
#pragma unroll
        for (int tc = 0; tc < 4; ++tc) {
            redS[wid][tc * 16 + lane] = ss[tc];
            redQ[wid][tc * 16 + lane] = qq[tc];
        }
    }
    __syncthreads();
    if (t < 64) {
        float ts = 0.f, t2 = 0.f;
#pragma unroll
        for (int k = 0; k < 8; ++k) {
            ts += redS[k][t];
            t2 += redQ[k][t];
        }
        atomicAdd(&statsOut[t], ts);
        atomicAdd(&statsOut[64 + t], t2);
    }
}

// ---------------- last-layer gdesc (BN2+ReLU, segmented sum, no h write) ----------------
#define CHK 16
__global__ void gdesc_last_kernel(const bf16_t* __restrict__ u, const float* __restrict__ stats,
                                  const float* __restrict__ g, const float* __restrict__ b,
                                  const int* __restrict__ batch, float* __restrict__ gdesc,
                                  int layer) {
    int lane = threadIdx.x & 63;
    int wid = threadIdx.x >> 6;
    int i0 = (blockIdx.x * 4 + wid) * CHK;
    if (i0 >= NN) return;
    float mu = stats[lane] * (1.0f / NN);
    float var = stats[64 + lane] * (1.0f / NN) - mu * mu;
    float a = g[lane] * rsqrtf(var + BN_EPS);
    float s = b[lane] - mu * a;
    int col = 1 + layer * HC + lane;
    float acc = 0.f;
    int cur = -1;
    int iend = i0 + CHK;
    if (iend > NN) iend = NN;
    for (int i = i0; i < iend; ++i) {
        int gid = batch[i];
        if (gid != cur) {
            if (cur >= 0) atomicAdd(&gdesc[cur * GD_COLS + col], acc);
            cur = gid;
            acc = 0.f;
        }
        acc += fmaxf(bf2f(u[i * HC + lane]) * a + s, 0.f);
    }
    if (cur >= 0) atomicAdd(&gdesc[cur * GD_COLS + col], acc);
}

__global__ void final_gemm_kernel(const float* __restrict__ gdesc, const float* __restrict__ lw,
                                  const float* __restrict__ lb, float* __restrict__ out) {
    int g = blockIdx.x;
    int lane = threadIdx.x;
    float a0 = 0.f, a1 = 0.f;
    for (int j = lane; j < GD_COLS; j += 64) {
        float v = gdesc[g * GD_COLS + j];
        a0 += v * lw[j * 2 + 0];
        a1 += v * lw[j * 2 + 1];
    }
    for (int off = 32; off > 0; off >>= 1) {
        a0 += __shfl_down(a0, off);
        a1 += __shfl_down(a1, off);
    }
    if (lane == 0) {
        out[g * 2 + 0] = a0 + lb[0];
        out[g * 2 + 1] = a1 + lb[1];
    }
}

extern "C" void kernel_launch(void* const* d_in, const int* in_sizes, int n_in, void* d_out,
                              int out_size, void* d_ws, size_t ws_size, hipStream_t stream) {
    const float* x = (const float*)d_in[0];
    const int* ei = (const int*)d_in[1];
    const int* batch = (const int*)d_in[2];
    const float* w1_0 = (const float*)d_in[3];
    const float* w1_rest = (const float*)d_in[4];
    const float* b1 = (const float*)d_in[5];
    const float* gm = (const float*)d_in[6];
    const float* bm = (const float*)d_in[7];
    const float* w2 = (const float*)d_in[8];
    const float* b2 = (const float*)d_in[9];
    const float* go = (const float*)d_in[10];
    const float* bo = (const float*)d_in[11];
    const float* lw = (const float*)d_in[12];
    const float* lb = (const float*)d_in[13];
    float* out = (float*)d_out;

    float* stats = (float*)d_ws;                     // NL*256
    float* gdesc = stats + NL * 256;                 // NG*321
    bf16_t* ybuf = (bf16_t*)(gdesc + (size_t)NG * GD_COLS + 64);  // NN*64 bf16
    bf16_t* ubuf = ybuf + (size_t)NN * HC;           // NN*64 bf16
    int* cnt = (int*)(ubuf + (size_t)NN * HC);       // NN
    unsigned short* ssrc = (unsigned short*)(cnt + NN);  // NN*64 ushort

    hipMemsetAsync(cnt, 0, NN * sizeof(int), stream);

    scatter_kernel<<<2048, 256, 0, stream>>>(ei, cnt, ssrc, stats, gdesc);

    layer0_kernel<<<(NN + 63) / 64, 256, 0, stream>>>(x, cnt, ssrc, w1_0, b1, batch, gdesc, ybuf,
                                                      stats);
    gemm128_norm_kernel<<<(NN + 127) / 128, 512, 0, stream>>>(ybuf, w2, b2, stats, gm, bm, ubuf,
                                                              stats + 128);
    for (int l = 1; l < NL; ++l) {
        float* st1 = stats + l * 256;
        float* st2 = st1 + 128;
        float* stPrev = stats + (l - 1) * 256 + 128;
        gather_gemm_kernel<<<(NN + 31) / 32, 256, 0, stream>>>(
            ubuf, stPrev, go + (l - 1) * HC, bo + (l - 1) * HC, cnt, ssrc,
            w1_rest + (size_t)(l - 1) * HC * HC, b1 + l * HC, batch, gdesc, l - 1, ybuf, st1);
        gemm128_norm_kernel<<<(NN + 127) / 128, 512, 0, stream>>>(
            ybuf, w2 + (size_t)l * HC * HC, b2 + l * HC, st1, gm + l * HC, bm + l * HC, ubuf, st2);
    }
    gdesc_last_kernel<<<(NN + 4 * CHK - 1) / (4 * CHK), 256, 0, stream>>>(
        ubuf, stats + 4 * 256 + 128, go + 4 * HC, bo + 4 * HC, batch, gdesc, 4);
    final_gemm_kernel<<<NG, 64, 0, stream>>>(gdesc, lw, lb, out);
}

// Round 15
// 450.721 us; speedup vs baseline: 1.6268x; 1.6268x over previous
//
#include <hip/hip_runtime.h>

#define NN 50000
#define NE 800000
#define NG 512
#define HC 64
#define NL 5
#define GD_COLS 321
#define BN_EPS 1e-5f
#define DEG_CAP 64  // max degree: Poisson(16), P(>64) ~ 1e-18 — fixed-stride edge table

#define SLICE 6250   // NN/8: destination slice per XCD group
#define ECHUNK 3125  // NE/256: edge chunk per block pair-group

typedef unsigned short bf16_t;
typedef unsigned int uiv4 __attribute__((ext_vector_type(4)));
typedef __attribute__((ext_vector_type(8))) short short8v;   // 8 bf16 = 4 VGPRs (MFMA A/B frag)
typedef __attribute__((ext_vector_type(4))) float f32x4;     // MFMA C/D frag
typedef __attribute__((ext_vector_type(4))) unsigned uint4v;

static __device__ __forceinline__ unsigned f2bfbits(float f) {
    unsigned u = __float_as_uint(f);
    return (u + 0x7FFFu + ((u >> 16) & 1u)) >> 16;
}
static __device__ __forceinline__ bf16_t f2bf(float f) { return (bf16_t)f2bfbits(f); }
static __device__ __forceinline__ float bf2f(bf16_t h) {
    return __uint_as_float(((unsigned)h) << 16);
}
static __device__ __forceinline__ float bflo(unsigned w) { return __uint_as_float(w << 16); }
static __device__ __forceinline__ float bfhi(unsigned w) {
    return __uint_as_float(w & 0xffff0000u);
}

// ---- shared MFMA GEMM phase (64 rows, 8 waves): OUT[64x64] = ZW @ WSM + bias + stats.
// zw: packed bf16 pairs, row-major [64 rows][33 words]. wsm: W columns as k-pair words.
// Wave wid owns tiles (tr=wid>>1, tc=(wid&1)*2 (+1)).
// A-frag: lane holds A[tr*16+(l&15)][kc*32+8*(l>>4)+0..7]. C/D: col=lane&15, row=(lane>>4)*4+j.
static __device__ __forceinline__ void mfma_gemm_phase(
    const unsigned* zw, const unsigned* wsm, const float* __restrict__ bias,
    bf16_t* __restrict__ out, float* __restrict__ statsOut, float (*redS)[64],
    float (*redQ)[64], int r0, int t, int lane, int wid) {
    int l15 = lane & 15, l4 = lane >> 4;
    int tr = wid >> 1;
    int tc0 = (wid & 1) * 2;
    f32x4 d0 = {0.f, 0.f, 0.f, 0.f}, d1 = {0.f, 0.f, 0.f, 0.f};
    const unsigned* arow = &zw[(tr * 16 + l15) * 33];
    const unsigned* brow0 = &wsm[(tc0 * 16 + l15) * 33];
    const unsigned* brow1 = &wsm[((tc0 + 1) * 16 + l15) * 33];
#pragma unroll
    for (int kc = 0; kc < 2; ++kc) {
        int kb = kc * 16 + l4 * 4;
        uint4v aw = {arow[kb], arow[kb + 1], arow[kb + 2], arow[kb + 3]};
        uint4v bw0 = {brow0[kb], brow0[kb + 1], brow0[kb + 2], brow0[kb + 3]};
        uint4v bw1 = {brow1[kb], brow1[kb + 1], brow1[kb + 2], brow1[kb + 3]};
        short8v af = __builtin_bit_cast(short8v, aw);
        d0 = __builtin_amdgcn_mfma_f32_16x16x32_bf16(af, __builtin_bit_cast(short8v, bw0), d0,
                                                     0, 0, 0);
        d1 = __builtin_amdgcn_mfma_f32_16x16x32_bf16(af, __builtin_bit_cast(short8v, bw1), d1,
                                                     0, 0, 0);
    }
    int c0 = tc0 * 16 + l15, c1 = c0 + 16;
    float bv0 = bias[c0], bv1 = bias[c1];
    float s0 = 0.f, q0 = 0.f, s1 = 0.f, q1 = 0.f;
#pragma unroll
    for (int j = 0; j < 4; ++j) {
        int gr = r0 + tr * 16 + l4 * 4 + j;
        if (gr < NN) {
            float v0 = d0[j] + bv0, v1 = d1[j] + bv1;
            out[(size_t)gr * HC + c0] = f2bf(v0);
            out[(size_t)gr * HC + c1] = f2bf(v1);
            s0 += v0;
            q0 += v0 * v0;
            s1 += v1;
            q1 += v1 * v1;
        }
    }
    s0 += __shfl_xor(s0, 16); s0 += __shfl_xor(s0, 32);
    q0 += __shfl_xor(q0, 16); q0 += __shfl_xor(q0, 32);
    s1 += __shfl_xor(s1, 16); s1 += __shfl_xor(s1, 32);
    q1 += __shfl_xor(q1, 16); q1 += __shfl_xor(q1, 32);
    if (l4 == 0) { redS[wid][c0] = s0; redQ[wid][c0] = q0; }
    else if (l4 == 1) { redS[wid][c1] = s1; redQ[wid][c1] = q1; }
    else if (l4 == 2) { redS[wid][c0 ^ 32] = 0.f; redQ[wid][c0 ^ 32] = 0.f; }
    else { redS[wid][c1 ^ 32] = 0.f; redQ[wid][c1 ^ 32] = 0.f; }
    __syncthreads();
    if (t < 64) {
        float ts = 0.f, t2 = 0.f;
#pragma unroll
        for (int k = 0; k < 8; ++k) {
            ts += redS[k][t];
            t2 += redQ[k][t];
        }
        atomicAdd(&statsOut[t], ts);
        atomicAdd(&statsOut[64 + t], t2);
    }
}

// ---------------- edge table build: XCD-sliced scatter + scratch zeroing ----------------
// Residual ~25 MB FETCH / ~30 MB WRITE matches memory-side atomic RMW (800K x 32B
// sectors); cache-policy levers proven ineffective (round 7). Near-floor.
__global__ __launch_bounds__(256) void scatter_kernel(const int* __restrict__ ei,
                                                      int* __restrict__ cnt,
                                                      unsigned short* __restrict__ ssrc,
                                                      float* __restrict__ stats,
                                                      float* __restrict__ gdesc) {
    int t = threadIdx.x;
    int g = blockIdx.x & 7;
    int c = blockIdx.x >> 3;
    int gt = blockIdx.x * 256 + t;
    int total = gridDim.x * 256;
    for (int i = gt; i < NL * 256; i += total) stats[i] = 0.f;
    for (int i = gt; i < NG * GD_COLS; i += total) gdesc[i] = 0.f;
    int lo = g * SLICE, hi = lo + SLICE;
    int e0 = c * ECHUNK;
    int e1 = e0 + ECHUNK;
    if (e1 > NE) e1 = NE;
    for (int e = e0 + t; e < e1; e += 256) {
        int d = ei[NE + e];
        if (d >= lo && d < hi) {
            int s = ei[e];
            int pos = atomicAdd(&cnt[d], 1);
            if (pos < DEG_CAP) ssrc[(d << 6) + pos] = (unsigned short)s;
        }
    }
}

// ---------------- layer 0: gather0 + rank-1 expand + stats0 + first_desc ----------------
__global__ __launch_bounds__(256) void layer0_kernel(
    const float* __restrict__ x, const int* __restrict__ cnt,
    const unsigned short* __restrict__ ssrc, const float* __restrict__ w,
    const float* __restrict__ bias, const int* __restrict__ batch, float* __restrict__ gdesc,
    bf16_t* __restrict__ y, float* __restrict__ stats) {
    __shared__ float z0p[256];
    __shared__ float z0s[64];
    int t = threadIdx.x, lane = t & 63, wid = t >> 6;
    int r0 = blockIdx.x * 64;
    if (t < 64) {
        int i = r0 + t;
        if (i < NN) atomicAdd(&gdesc[batch[i] * GD_COLS], x[i]);
    }
    {
        int node = t >> 2, sub = t & 3;
        int i = r0 + node;
        float acc = 0.f;
        if (i < NN) {
            int deg = cnt[i];
            if (deg > DEG_CAP) deg = DEG_CAP;
            int pa = i << 6;
            for (int p = sub; p < deg; p += 4) acc += x[ssrc[pa + p]];
            if (sub == 0) acc += x[i];
        }
        z0p[t] = acc;
    }
    __syncthreads();
    if (t < 64) z0s[t] = z0p[4 * t] + z0p[4 * t + 1] + z0p[4 * t + 2] + z0p[4 * t + 3];
    __syncthreads();
    float wv = w[lane], bv = bias[lane];
    float s = 0.f, s2 = 0.f;
    for (int j = 0; j < 16; ++j) {
        int r = r0 + wid * 16 + j;
        if (r < NN) {
            float v = z0s[wid * 16 + j] * wv + bv;
            y[r * HC + lane] = f2bf(v);
            s += v;
            s2 += v * v;
        }
    }
    __shared__ float ls[256], ls2[256];
    ls[t] = s;
    ls2[t] = s2;
    __syncthreads();
    if (wid == 0) {
        float ts = ls[lane] + ls[64 + lane] + ls[128 + lane] + ls[192 + lane];
        float t2 = ls2[lane] + ls2[64 + lane] + ls2[128 + lane] + ls2[192 + lane];
        atomicAdd(&stats[lane], ts);
        atomicAdd(&stats[64 + lane], t2);
    }
}

// ------- act+gdesc: h = relu(BN2(u)) once per node; segmented gdesc; optional hbuf -----
// Replaces gather's per-edge activation (16x redundant) and gather's Phase A.
// hout==nullptr for the last layer (== old gdesc_last).
#define CHK 16
__global__ void act_gdesc_kernel(const bf16_t* __restrict__ u, const float* __restrict__ stats,
                                 const float* __restrict__ g, const float* __restrict__ b,
                                 const int* __restrict__ batch, float* __restrict__ gdesc,
                                 int layer, bf16_t* __restrict__ hout) {
    int lane = threadIdx.x & 63;
    int wid = threadIdx.x >> 6;
    int i0 = (blockIdx.x * 4 + wid) * CHK;
    if (i0 >= NN) return;
    float mu = stats[lane] * (1.0f / NN);
    float var = stats[64 + lane] * (1.0f / NN) - mu * mu;
    float a = g[lane] * rsqrtf(var + BN_EPS);
    float s = b[lane] - mu * a;
    int col = 1 + layer * HC + lane;
    float acc = 0.f;
    int cur = -1;
    int iend = i0 + CHK;
    if (iend > NN) iend = NN;
    for (int i = i0; i < iend; ++i) {
        int gid = batch[i];
        if (gid != cur) {
            if (cur >= 0) atomicAdd(&gdesc[cur * GD_COLS + col], acc);
            cur = gid;
            acc = 0.f;
        }
        float hv = fmaxf(bf2f(u[(size_t)i * HC + lane]) * a + s, 0.f);
        if (hout) hout[(size_t)i * HC + lane] = f2bf(hv);
        acc += hv;
    }
    if (cur >= 0) atomicAdd(&gdesc[cur * GD_COLS + col], acc);
}

// ---------------- K1: pre-activated gather (plain sums) + MFMA GEMM1 + stats1 ----------
// Round-11 structure (512 thr, 8 waves x 8 rows, rv0 hoist, (512,2) — VGPR headroom,
// round-14's pinned cap caused spills). Input is hbuf = relu(BN2(u)) precomputed by
// act_gdesc_kernel: inner loop is pure bf16-unpack+add (no fma/max, no BN setup,
// no Phase A — gdesc moved to act_gdesc).
__global__ __launch_bounds__(512, 2) void gather_gemm_kernel(
    const bf16_t* __restrict__ h, const int* __restrict__ cnt,
    const unsigned short* __restrict__ ssrc, const float* __restrict__ w,
    const float* __restrict__ bias, bf16_t* __restrict__ out, float* __restrict__ statsOut) {
    __shared__ unsigned zw[64 * 33];
    __shared__ unsigned wsm[64 * 33];
    __shared__ float redS[8][64], redQ[8][64];
    int t = threadIdx.x, lane = t & 63, wid = t >> 6;
    int r0 = blockIdx.x * 64;
    int li = lane & 7;       // channel slice owner
    int gq = lane >> 3;      // row within wave's 8
    int gbase = lane & 56;   // first lane of this 8-lane group
    int nB = r0 + wid * 8 + gq;
    uiv4 myidx = {0, 0, 0, 0};
    uiv4 selfv = {0, 0, 0, 0};
    int degB = 0;
    if (nB < NN) {
        degB = cnt[nB];
        if (degB > DEG_CAP) degB = DEG_CAP;
        myidx = *(const uiv4*)&ssrc[((size_t)nB << 6) + li * 8];
        selfv = *(const uiv4*)&h[(size_t)nB * HC + li * 8];
    }
    // --- hoisted batch-0 gather loads (masked lanes read h[0..] harmlessly) ---
    uiv4 rv0[8];
    {
        unsigned w0 = __shfl(myidx[0], gbase);
        unsigned w1 = __shfl(myidx[1], gbase);
        unsigned w2 = __shfl(myidx[2], gbase);
        unsigned w3 = __shfl(myidx[3], gbase);
        int id[8] = {(int)(w0 & 0xffff), (int)(w0 >> 16), (int)(w1 & 0xffff),
                     (int)(w1 >> 16),    (int)(w2 & 0xffff), (int)(w2 >> 16),
                     (int)(w3 & 0xffff), (int)(w3 >> 16)};
#pragma unroll
        for (int e = 0; e < 8; ++e)
            rv0[e] = *(const uiv4*)&h[(size_t)id[e] * HC + li * 8];
    }
    for (int idx = t; idx < 2048; idx += 512) {
        int kk = idx >> 6, c = idx & 63;
        unsigned lo = f2bfbits(w[(2 * kk) * 64 + c]);
        unsigned hi = f2bfbits(w[(2 * kk + 1) * 64 + c]);
        wsm[c * 33 + kk] = lo | (hi << 16);
    }
    // Phase B: self term + plain neighbor sums (values are pre-activated bf16)
    {
        float acc[8];
        if (nB < NN) {
            acc[0] = bflo(selfv[0]);
            acc[1] = bfhi(selfv[0]);
            acc[2] = bflo(selfv[1]);
            acc[3] = bfhi(selfv[1]);
            acc[4] = bflo(selfv[2]);
            acc[5] = bfhi(selfv[2]);
            acc[6] = bflo(selfv[3]);
            acc[7] = bfhi(selfv[3]);
        } else {
#pragma unroll
            for (int c = 0; c < 8; ++c) acc[c] = 0.f;
        }
        if (degB > 0) {
            uiv4 rv[8];
#pragma unroll
            for (int e = 0; e < 8; ++e) rv[e] = rv0[e];
            int cntA = degB < 8 ? degB : 8;
            for (int b = 1; cntA > 0; ++b) {
                uiv4 nv[8];
                int cntB = 0;
                if (b * 8 < degB) {
                    unsigned w0 = __shfl(myidx[0], gbase + b);
                    unsigned w1 = __shfl(myidx[1], gbase + b);
                    unsigned w2 = __shfl(myidx[2], gbase + b);
                    unsigned w3 = __shfl(myidx[3], gbase + b);
                    int id[8] = {(int)(w0 & 0xffff), (int)(w0 >> 16), (int)(w1 & 0xffff),
                                 (int)(w1 >> 16),    (int)(w2 & 0xffff), (int)(w2 >> 16),
                                 (int)(w3 & 0xffff), (int)(w3 >> 16)};
#pragma unroll
                    for (int e = 0; e < 8; ++e)
                        nv[e] = *(const uiv4*)&h[(size_t)id[e] * HC + li * 8];
                    cntB = degB - b * 8;
                    if (cntB > 8) cntB = 8;
                }
#pragma unroll
                for (int e = 0; e < 8; ++e) {
                    float v0 = bflo(rv[e][0]);
                    float v1 = bfhi(rv[e][0]);
                    float v2 = bflo(rv[e][1]);
                    float v3 = bfhi(rv[e][1]);
                    float v4 = bflo(rv[e][2]);
                    float v5 = bfhi(rv[e][2]);
                    float v6 = bflo(rv[e][3]);
                    float v7 = bfhi(rv[e][3]);
                    if (e < cntA) {
                        acc[0] += v0;
                        acc[1] += v1;
                        acc[2] += v2;
                        acc[3] += v3;
                        acc[4] += v4;
                        acc[5] += v5;
                        acc[6] += v6;
                        acc[7] += v7;
                    }
                }
#pragma unroll
                for (int e = 0; e < 8; ++e) rv[e] = nv[e];
                cntA = cntB;
            }
        }
        int lr = wid * 8 + gq;
        unsigned* zp = &zw[lr * 33 + li * 4];
        zp[0] = f2bfbits(acc[0]) | (f2bfbits(acc[1]) << 16);
        zp[1] = f2bfbits(acc[2]) | (f2bfbits(acc[3]) << 16);
        zp[2] = f2bfbits(acc[4]) | (f2bfbits(acc[5]) << 16);
        zp[3] = f2bfbits(acc[6]) | (f2bfbits(acc[7]) << 16);
    }
    __syncthreads();  // zw rows cross waves for MFMA A-frags
    mfma_gemm_phase(zw, wsm, bias, out, statsOut, redS, redQ, r0, t, lane, wid);
}

// ---------------- K2: BN1+ReLU staging + MFMA GEMM2 + stats2 (128 rows/block) ----------
__global__ __launch_bounds__(512) void gemm128_norm_kernel(
    const bf16_t* __restrict__ in, const float* __restrict__ w, const float* __restrict__ bias,
    const float* __restrict__ statsIn, const float* __restrict__ gIn,
    const float* __restrict__ bIn, bf16_t* __restrict__ out, float* __restrict__ statsOut) {
    __shared__ unsigned zw[128 * 33];
    __shared__ unsigned wsm[64 * 33];
    __shared__ float a1[64], s1[64];
    __shared__ float redS[8][64], redQ[8][64];
    int t = threadIdx.x, lane = t & 63, wid = t >> 6;
    int r0 = blockIdx.x * 128;
    if (t < 64) {
        float mu = statsIn[t] * (1.0f / NN);
        float var = statsIn[64 + t] * (1.0f / NN) - mu * mu;
        float a = gIn[t] * rsqrtf(var + BN_EPS);
        a1[t] = a;
        s1[t] = bIn[t] - mu * a;
    }
    for (int idx = t; idx < 2048; idx += 512) {
        int kk = idx >> 6, c = idx & 63;
        unsigned lo = f2bfbits(w[(2 * kk) * 64 + c]);
        unsigned hi = f2bfbits(w[(2 * kk + 1) * 64 + c]);
        wsm[c * 33 + kk] = lo | (hi << 16);
    }
    __syncthreads();
    for (int idx = t; idx < 1024; idx += 512) {
        int off = idx * 8;
        int r = off >> 6;
        int k = off & 63;
        uiv4 wv4 = {0u, 0u, 0u, 0u};
        int gr = r0 + r;
        if (gr < NN) wv4 = *(const uiv4*)&in[(size_t)gr * HC + k];
        unsigned* zp = &zw[r * 33 + (k >> 1)];
#pragma unroll
        for (int j = 0; j < 4; ++j) {
            unsigned word = wv4[j];
            int kk = k + 2 * j;
            float v0 = fmaxf(bflo(word) * a1[kk] + s1[kk], 0.f);
            float v1 = fmaxf(bfhi(word) * a1[kk + 1] + s1[kk + 1], 0.f);
            zp[j] = f2bfbits(v0) | (f2bfbits(v1) << 16);
        }
    }
    __syncthreads();
    int l15 = lane & 15, l4 = lane >> 4;
    const unsigned* arow = &zw[(wid * 16 + l15) * 33];
    f32x4 d[4];
#pragma unroll
    for (int tc = 0; tc < 4; ++tc) d[tc] = (f32x4){0.f, 0.f, 0.f, 0.f};
#pragma unroll
    for (int kc = 0; kc < 2; ++kc) {
        int kb = kc * 16 + l4 * 4;
        uint4v aw = {arow[kb], arow[kb + 1], arow[kb + 2], arow[kb + 3]};
        short8v af = __builtin_bit_cast(short8v, aw);
#pragma unroll
        for (int tc = 0; tc < 4; ++tc) {
            const unsigned* brow = &wsm[(tc * 16 + l15) * 33];
            uint4v bw = {brow[kb], brow[kb + 1], brow[kb + 2], brow[kb + 3]};
            d[tc] = __builtin_amdgcn_mfma_f32_16x16x32_bf16(af, __builtin_bit_cast(short8v, bw),
                                                            d[tc], 0, 0, 0);
        }
    }
    float ss[4], qq[4];
#pragma unroll
    for (int tc = 0; tc < 4; ++tc) {
        int cc = tc * 16 + l15;
        float bv = bias[cc];
        float s = 0.f, q = 0.f;
#pragma unroll
        for (int j = 0; j < 4; ++j) {
            int gr = r0 + wid * 16 + l4 * 4 + j;
            if (gr < NN) {
                float v = d[tc][j] + bv;
                out[(size_t)gr * HC + cc] = f2bf(v);
                s += v;
                q += v * v;
            }
        }
        s += __shfl_xor(s, 16); s += __shfl_xor(s, 32);
        q += __shfl_xor(q, 16); q += __shfl_xor(q, 32);
        ss[tc] = s;
        qq[tc] = q;
    }
    if (lane < 16) {
#pragma unroll
        for (int tc = 0; tc < 4; ++tc) {
            redS[wid][tc * 16 + lane] = ss[tc];
            redQ[wid][tc * 16 + lane] = qq[tc];
        }
    }
    __syncthreads();
    if (t < 64) {
        float ts = 0.f, t2 = 0.f;
#pragma unroll
        for (int k = 0; k < 8; ++k) {
            ts += redS[k][t];
            t2 += redQ[k][t];
        }
        atomicAdd(&statsOut[t], ts);
        atomicAdd(&statsOut[64 + t], t2);
    }
}

__global__ void final_gemm_kernel(const float* __restrict__ gdesc, const float* __restrict__ lw,
                                  const float* __restrict__ lb, float* __restrict__ out) {
    int g = blockIdx.x;
    int lane = threadIdx.x;
    float a0 = 0.f, a1 = 0.f;
    for (int j = lane; j < GD_COLS; j += 64) {
        float v = gdesc[g * GD_COLS + j];
        a0 += v * lw[j * 2 + 0];
        a1 += v * lw[j * 2 + 1];
    }
    for (int off = 32; off > 0; off >>= 1) {
        a0 += __shfl_down(a0, off);
        a1 += __shfl_down(a1, off);
    }
    if (lane == 0) {
        out[g * 2 + 0] = a0 + lb[0];
        out[g * 2 + 1] = a1 + lb[1];
    }
}

extern "C" void kernel_launch(void* const* d_in, const int* in_sizes, int n_in, void* d_out,
                              int out_size, void* d_ws, size_t ws_size, hipStream_t stream) {
    const float* x = (const float*)d_in[0];
    const int* ei = (const int*)d_in[1];
    const int* batch = (const int*)d_in[2];
    const float* w1_0 = (const float*)d_in[3];
    const float* w1_rest = (const float*)d_in[4];
    const float* b1 = (const float*)d_in[5];
    const float* gm = (const float*)d_in[6];
    const float* bm = (const float*)d_in[7];
    const float* w2 = (const float*)d_in[8];
    const float* b2 = (const float*)d_in[9];
    const float* go = (const float*)d_in[10];
    const float* bo = (const float*)d_in[11];
    const float* lw = (const float*)d_in[12];
    const float* lb = (const float*)d_in[13];
    float* out = (float*)d_out;

    float* stats = (float*)d_ws;                     // NL*256
    float* gdesc = stats + NL * 256;                 // NG*321
    bf16_t* ybuf = (bf16_t*)(gdesc + (size_t)NG * GD_COLS + 64);  // NN*64 bf16
    bf16_t* ubuf = ybuf + (size_t)NN * HC;           // NN*64 bf16
    int* cnt = (int*)(ubuf + (size_t)NN * HC);       // NN
    unsigned short* ssrc = (unsigned short*)(cnt + NN);  // NN*64 ushort
    bf16_t* hbuf = (bf16_t*)(ssrc + (size_t)NN * 64);    // NN*64 bf16 (pre-activated)

    hipMemsetAsync(cnt, 0, NN * sizeof(int), stream);

    scatter_kernel<<<2048, 256, 0, stream>>>(ei, cnt, ssrc, stats, gdesc);

    layer0_kernel<<<(NN + 63) / 64, 256, 0, stream>>>(x, cnt, ssrc, w1_0, b1, batch, gdesc, ybuf,
                                                      stats);
    gemm128_norm_kernel<<<(NN + 127) / 128, 512, 0, stream>>>(ybuf, w2, b2, stats, gm, bm, ubuf,
                                                              stats + 128);
    for (int l = 1; l < NL; ++l) {
        float* st1 = stats + l * 256;
        float* st2 = st1 + 128;
        float* stPrev = stats + (l - 1) * 256 + 128;
        act_gdesc_kernel<<<(NN + 4 * CHK - 1) / (4 * CHK), 256, 0, stream>>>(
            ubuf, stPrev, go + (l - 1) * HC, bo + (l - 1) * HC, batch, gdesc, l - 1, hbuf);
        gather_gemm_kernel<<<(NN + 63) / 64, 512, 0, stream>>>(
            hbuf, cnt, ssrc, w1_rest + (size_t)(l - 1) * HC * HC, b1 + l * HC, ybuf, st1);
        gemm128_norm_kernel<<<(NN + 127) / 128, 512, 0, stream>>>(
            ybuf, w2 + (size_t)l * HC * HC, b2 + l * HC, st1, gm + l * HC, bm + l * HC, ubuf, st2);
    }
    act_gdesc_kernel<<<(NN + 4 * CHK - 1) / (4 * CHK), 256, 0, stream>>>(
        ubuf, stats + 4 * 256 + 128, go + 4 * HC, bo + 4 * HC, batch, gdesc, 4, nullptr);
    final_gemm_kernel<<<NG, 64, 0, stream>>>(gdesc, lw, lb, out);
}

// Round 16
// 401.193 us; speedup vs baseline: 1.8276x; 1.1235x over previous
//
#include <hip/hip_runtime.h>

#define NN 50000
#define NE 800000
#define NG 512
#define HC 64
#define NL 5
#define GD_COLS 321
#define BN_EPS 1e-5f
#define DEG_CAP 64  // max degree: Poisson(16), P(>64) ~ 1e-18 — fixed-stride edge table

#define SLICE 6250   // NN/8: destination slice per XCD group
#define ECHUNK 3125  // NE/256: edge chunk per block pair-group

typedef unsigned short bf16_t;
typedef unsigned int uiv4 __attribute__((ext_vector_type(4)));
typedef __attribute__((ext_vector_type(8))) short short8v;   // 8 bf16 = 4 VGPRs (MFMA A/B frag)
typedef __attribute__((ext_vector_type(4))) float f32x4;     // MFMA C/D frag
typedef __attribute__((ext_vector_type(4))) unsigned uint4v;

static __device__ __forceinline__ unsigned f2bfbits(float f) {
    unsigned u = __float_as_uint(f);
    return (u + 0x7FFFu + ((u >> 16) & 1u)) >> 16;
}
static __device__ __forceinline__ bf16_t f2bf(float f) { return (bf16_t)f2bfbits(f); }
static __device__ __forceinline__ float bf2f(bf16_t h) {
    return __uint_as_float(((unsigned)h) << 16);
}
static __device__ __forceinline__ float bflo(unsigned w) { return __uint_as_float(w << 16); }
static __device__ __forceinline__ float bfhi(unsigned w) {
    return __uint_as_float(w & 0xffff0000u);
}

// ---- shared MFMA GEMM phase (64 rows, 8 waves): OUT[64x64] = ZW @ WSM + bias + stats.
// zw: packed bf16 pairs, row-major [64 rows][33 words]. wsm: W columns as k-pair words.
// Wave wid owns tiles (tr=wid>>1, tc=(wid&1)*2 (+1)).
// A-frag: lane holds A[tr*16+(l&15)][kc*32+8*(l>>4)+0..7]. C/D: col=lane&15, row=(lane>>4)*4+j.
static __device__ __forceinline__ void mfma_gemm_phase(
    const unsigned* zw, const unsigned* wsm, const float* __restrict__ bias,
    bf16_t* __restrict__ out, float* __restrict__ statsOut, float (*redS)[64],
    float (*redQ)[64], int r0, int t, int lane, int wid) {
    int l15 = lane & 15, l4 = lane >> 4;
    int tr = wid >> 1;
    int tc0 = (wid & 1) * 2;
    f32x4 d0 = {0.f, 0.f, 0.f, 0.f}, d1 = {0.f, 0.f, 0.f, 0.f};
    const unsigned* arow = &zw[(tr * 16 + l15) * 33];
    const unsigned* brow0 = &wsm[(tc0 * 16 + l15) * 33];
    const unsigned* brow1 = &wsm[((tc0 + 1) * 16 + l15) * 33];
#pragma unroll
    for (int kc = 0; kc < 2; ++kc) {
        int kb = kc * 16 + l4 * 4;
        uint4v aw = {arow[kb], arow[kb + 1], arow[kb + 2], arow[kb + 3]};
        uint4v bw0 = {brow0[kb], brow0[kb + 1], brow0[kb + 2], brow0[kb + 3]};
        uint4v bw1 = {brow1[kb], brow1[kb + 1], brow1[kb + 2], brow1[kb + 3]};
        short8v af = __builtin_bit_cast(short8v, aw);
        d0 = __builtin_amdgcn_mfma_f32_16x16x32_bf16(af, __builtin_bit_cast(short8v, bw0), d0,
                                                     0, 0, 0);
        d1 = __builtin_amdgcn_mfma_f32_16x16x32_bf16(af, __builtin_bit_cast(short8v, bw1), d1,
                                                     0, 0, 0);
    }
    int c0 = tc0 * 16 + l15, c1 = c0 + 16;
    float bv0 = bias[c0], bv1 = bias[c1];
    float s0 = 0.f, q0 = 0.f, s1 = 0.f, q1 = 0.f;
#pragma unroll
    for (int j = 0; j < 4; ++j) {
        int gr = r0 + tr * 16 + l4 * 4 + j;
        if (gr < NN) {
            float v0 = d0[j] + bv0, v1 = d1[j] + bv1;
            out[(size_t)gr * HC + c0] = f2bf(v0);
            out[(size_t)gr * HC + c1] = f2bf(v1);
            s0 += v0;
            q0 += v0 * v0;
            s1 += v1;
            q1 += v1 * v1;
        }
    }
    s0 += __shfl_xor(s0, 16); s0 += __shfl_xor(s0, 32);
    q0 += __shfl_xor(q0, 16); q0 += __shfl_xor(q0, 32);
    s1 += __shfl_xor(s1, 16); s1 += __shfl_xor(s1, 32);
    q1 += __shfl_xor(q1, 16); q1 += __shfl_xor(q1, 32);
    if (l4 == 0) { redS[wid][c0] = s0; redQ[wid][c0] = q0; }
    else if (l4 == 1) { redS[wid][c1] = s1; redQ[wid][c1] = q1; }
    else if (l4 == 2) { redS[wid][c0 ^ 32] = 0.f; redQ[wid][c0 ^ 32] = 0.f; }
    else { redS[wid][c1 ^ 32] = 0.f; redQ[wid][c1 ^ 32] = 0.f; }
    __syncthreads();
    if (t < 64) {
        float ts = 0.f, t2 = 0.f;
#pragma unroll
        for (int k = 0; k < 8; ++k) {
            ts += redS[k][t];
            t2 += redQ[k][t];
        }
        atomicAdd(&statsOut[t], ts);
        atomicAdd(&statsOut[64 + t], t2);
    }
}

// ---------------- edge table build: XCD-sliced scatter + scratch zeroing ----------------
// grid = 256 chunks x 8 groups; g = blockIdx&7 ~ XCD id. Residual ~25 MB FETCH / ~30 MB
// WRITE matches memory-side atomic RMW (800K x 32B sectors); cache-policy levers proven
// ineffective (round 7). Near-floor pending an atomic-free algorithm.
__global__ __launch_bounds__(256) void scatter_kernel(const int* __restrict__ ei,
                                                      int* __restrict__ cnt,
                                                      unsigned short* __restrict__ ssrc,
                                                      float* __restrict__ stats,
                                                      float* __restrict__ gdesc) {
    int t = threadIdx.x;
    int g = blockIdx.x & 7;
    int c = blockIdx.x >> 3;
    int gt = blockIdx.x * 256 + t;
    int total = gridDim.x * 256;
    for (int i = gt; i < NL * 256; i += total) stats[i] = 0.f;
    for (int i = gt; i < NG * GD_COLS; i += total) gdesc[i] = 0.f;
    int lo = g * SLICE, hi = lo + SLICE;
    int e0 = c * ECHUNK;
    int e1 = e0 + ECHUNK;
    if (e1 > NE) e1 = NE;
    for (int e = e0 + t; e < e1; e += 256) {
        int d = ei[NE + e];
        if (d >= lo && d < hi) {
            int s = ei[e];
            int pos = atomicAdd(&cnt[d], 1);
            if (pos < DEG_CAP) ssrc[(d << 6) + pos] = (unsigned short)s;
        }
    }
}

// ---------------- layer 0: gather0 + rank-1 expand + stats0 + first_desc ----------------
__global__ __launch_bounds__(256) void layer0_kernel(
    const float* __restrict__ x, const int* __restrict__ cnt,
    const unsigned short* __restrict__ ssrc, const float* __restrict__ w,
    const float* __restrict__ bias, const int* __restrict__ batch, float* __restrict__ gdesc,
    bf16_t* __restrict__ y, float* __restrict__ stats) {
    __shared__ float z0p[256];
    __shared__ float z0s[64];
    int t = threadIdx.x, lane = t & 63, wid = t >> 6;
    int r0 = blockIdx.x * 64;
    if (t < 64) {
        int i = r0 + t;
        if (i < NN) atomicAdd(&gdesc[batch[i] * GD_COLS], x[i]);
    }
    {
        int node = t >> 2, sub = t & 3;
        int i = r0 + node;
        float acc = 0.f;
        if (i < NN) {
            int deg = cnt[i];
            if (deg > DEG_CAP) deg = DEG_CAP;
            int pa = i << 6;
            for (int p = sub; p < deg; p += 4) acc += x[ssrc[pa + p]];
            if (sub == 0) acc += x[i];
        }
        z0p[t] = acc;
    }
    __syncthreads();
    if (t < 64) z0s[t] = z0p[4 * t] + z0p[4 * t + 1] + z0p[4 * t + 2] + z0p[4 * t + 3];
    __syncthreads();
    float wv = w[lane], bv = bias[lane];
    float s = 0.f, s2 = 0.f;
    for (int j = 0; j < 16; ++j) {
        int r = r0 + wid * 16 + j;
        if (r < NN) {
            float v = z0s[wid * 16 + j] * wv + bv;
            y[r * HC + lane] = f2bf(v);
            s += v;
            s2 += v * v;
        }
    }
    __shared__ float ls[256], ls2[256];
    ls[t] = s;
    ls2[t] = s2;
    __syncthreads();
    if (wid == 0) {
        float ts = ls[lane] + ls[64 + lane] + ls[128 + lane] + ls[192 + lane];
        float t2 = ls2[lane] + ls2[64 + lane] + ls2[128 + lane] + ls2[192 + lane];
        atomicAdd(&stats[lane], ts);
        atomicAdd(&stats[64 + lane], t2);
    }
}

// ---------------- K1: BN2(prev)+ReLU fused gather + gdesc(prev) + MFMA GEMM1 + stats1 ----
// The 403.3 µs configuration: 512 thr, 8 waves x 8 rows, SINGLE rv0 hoist, (512,2)
// (VGPR 60 — under the 64-VGPR occupancy cliff; every other occupancy/balance/VALU
// lever measured net-negative in rounds 9/10/12/13/14/15).
__global__ __launch_bounds__(512, 2) void gather_gemm_kernel(
    const bf16_t* __restrict__ u, const float* __restrict__ statsPrev,
    const float* __restrict__ gPrev, const float* __restrict__ bPrev,
    const int* __restrict__ cnt, const unsigned short* __restrict__ ssrc,
    const float* __restrict__ w, const float* __restrict__ bias, const int* __restrict__ batch,
    float* __restrict__ gdesc, int layerPrev, bf16_t* __restrict__ out,
    float* __restrict__ statsOut) {
    __shared__ unsigned zw[64 * 33];
    __shared__ unsigned wsm[64 * 33];
    __shared__ float a1[64], s1[64];
    __shared__ float redS[8][64], redQ[8][64];
    int t = threadIdx.x, lane = t & 63, wid = t >> 6;
    int r0 = blockIdx.x * 64;
    int li = lane & 7;       // channel slice owner
    int gq = lane >> 3;      // row within wave's 8
    int gbase = lane & 56;   // first lane of this 8-lane group
    int nB = r0 + wid * 8 + gq;
    uiv4 myidx = {0, 0, 0, 0};
    uiv4 selfv = {0, 0, 0, 0};
    int degB = 0;
    if (nB < NN) {
        degB = cnt[nB];
        if (degB > DEG_CAP) degB = DEG_CAP;
        myidx = *(const uiv4*)&ssrc[((size_t)nB << 6) + li * 8];
        selfv = *(const uiv4*)&u[(size_t)nB * HC + li * 8];
    }
    // --- hoisted batch-0 gather loads (masked lanes read u[0..] harmlessly) ---
    uiv4 rv0[8];
    {
        unsigned w0 = __shfl(myidx[0], gbase);
        unsigned w1 = __shfl(myidx[1], gbase);
        unsigned w2 = __shfl(myidx[2], gbase);
        unsigned w3 = __shfl(myidx[3], gbase);
        int id[8] = {(int)(w0 & 0xffff), (int)(w0 >> 16), (int)(w1 & 0xffff),
                     (int)(w1 >> 16),    (int)(w2 & 0xffff), (int)(w2 >> 16),
                     (int)(w3 & 0xffff), (int)(w3 >> 16)};
#pragma unroll
        for (int e = 0; e < 8; ++e)
            rv0[e] = *(const uiv4*)&u[(size_t)id[e] * HC + li * 8];
    }
    if (t < 64) {
        float mu = statsPrev[t] * (1.0f / NN);
        float var = statsPrev[64 + t] * (1.0f / NN) - mu * mu;
        float a = gPrev[t] * rsqrtf(var + BN_EPS);
        a1[t] = a;
        s1[t] = bPrev[t] - mu * a;
    }
    for (int idx = t; idx < 2048; idx += 512) {
        int kk = idx >> 6, c = idx & 63;
        unsigned lo = f2bfbits(w[(2 * kk) * 64 + c]);
        unsigned hi = f2bfbits(w[(2 * kk + 1) * 64 + c]);
        wsm[c * 33 + kk] = lo | (hi << 16);
    }
    __syncthreads();
    // Phase B: self-term init + edge gather (8-lane groups, shfl-broadcast indices)
    {
        float a8[8], s8[8];
#pragma unroll
        for (int c = 0; c < 8; ++c) {
            a8[c] = a1[li * 8 + c];
            s8[c] = s1[li * 8 + c];
        }
        float acc[8];
        if (nB < NN) {
            acc[0] = fmaxf(bflo(selfv[0]) * a8[0] + s8[0], 0.f);
            acc[1] = fmaxf(bfhi(selfv[0]) * a8[1] + s8[1], 0.f);
            acc[2] = fmaxf(bflo(selfv[1]) * a8[2] + s8[2], 0.f);
            acc[3] = fmaxf(bfhi(selfv[1]) * a8[3] + s8[3], 0.f);
            acc[4] = fmaxf(bflo(selfv[2]) * a8[4] + s8[4], 0.f);
            acc[5] = fmaxf(bfhi(selfv[2]) * a8[5] + s8[5], 0.f);
            acc[6] = fmaxf(bflo(selfv[3]) * a8[6] + s8[6], 0.f);
            acc[7] = fmaxf(bfhi(selfv[3]) * a8[7] + s8[7], 0.f);
        } else {
#pragma unroll
            for (int c = 0; c < 8; ++c) acc[c] = 0.f;
        }
        if (degB > 0) {
            uiv4 rv[8];
#pragma unroll
            for (int e = 0; e < 8; ++e) rv[e] = rv0[e];
            int cntA = degB < 8 ? degB : 8;
            for (int b = 1; cntA > 0; ++b) {
                uiv4 nv[8];
                int cntB = 0;
                if (b * 8 < degB) {
                    unsigned w0 = __shfl(myidx[0], gbase + b);
                    unsigned w1 = __shfl(myidx[1], gbase + b);
                    unsigned w2 = __shfl(myidx[2], gbase + b);
                    unsigned w3 = __shfl(myidx[3], gbase + b);
                    int id[8] = {(int)(w0 & 0xffff), (int)(w0 >> 16), (int)(w1 & 0xffff),
                                 (int)(w1 >> 16),    (int)(w2 & 0xffff), (int)(w2 >> 16),
                                 (int)(w3 & 0xffff), (int)(w3 >> 16)};
#pragma unroll
                    for (int e = 0; e < 8; ++e)
                        nv[e] = *(const uiv4*)&u[(size_t)id[e] * HC + li * 8];
                    cntB = degB - b * 8;
                    if (cntB > 8) cntB = 8;
                }
#pragma unroll
                for (int e = 0; e < 8; ++e) {
                    float v0 = fmaxf(bflo(rv[e][0]) * a8[0] + s8[0], 0.f);
                    float v1 = fmaxf(bfhi(rv[e][0]) * a8[1] + s8[1], 0.f);
                    float v2 = fmaxf(bflo(rv[e][1]) * a8[2] + s8[2], 0.f);
                    float v3 = fmaxf(bfhi(rv[e][1]) * a8[3] + s8[3], 0.f);
                    float v4 = fmaxf(bflo(rv[e][2]) * a8[4] + s8[4], 0.f);
                    float v5 = fmaxf(bfhi(rv[e][2]) * a8[5] + s8[5], 0.f);
                    float v6 = fmaxf(bflo(rv[e][3]) * a8[6] + s8[6], 0.f);
                    float v7 = fmaxf(bfhi(rv[e][3]) * a8[7] + s8[7], 0.f);
                    if (e < cntA) {
                        acc[0] += v0;
                        acc[1] += v1;
                        acc[2] += v2;
                        acc[3] += v3;
                        acc[4] += v4;
                        acc[5] += v5;
                        acc[6] += v6;
                        acc[7] += v7;
                    }
                }
#pragma unroll
                for (int e = 0; e < 8; ++e) rv[e] = nv[e];
                cntA = cntB;
            }
        }
        int lr = wid * 8 + gq;
        unsigned* zp = &zw[lr * 33 + li * 4];
        zp[0] = f2bfbits(acc[0]) | (f2bfbits(acc[1]) << 16);
        zp[1] = f2bfbits(acc[2]) | (f2bfbits(acc[3]) << 16);
        zp[2] = f2bfbits(acc[4]) | (f2bfbits(acc[5]) << 16);
        zp[3] = f2bfbits(acc[6]) | (f2bfbits(acc[7]) << 16);
    }
    // Phase A: gdesc segmented sum only (lane = channel)
    {
        float av = a1[lane], sv = s1[lane];
        int col = 1 + layerPrev * HC + lane;
        float gacc = 0.f;
        int cur = -1;
        for (int j = 0; j < 8; ++j) {
            int gr = r0 + wid * 8 + j;
            if (gr < NN) {
                float hv = fmaxf(bf2f(u[(size_t)gr * HC + lane]) * av + sv, 0.f);
                int gid = batch[gr];
                if (gid != cur) {
                    if (cur >= 0) atomicAdd(&gdesc[cur * GD_COLS + col], gacc);
                    cur = gid;
                    gacc = 0.f;
                }
                gacc += hv;
            }
        }
        if (cur >= 0) atomicAdd(&gdesc[cur * GD_COLS + col], gacc);
    }
    __syncthreads();  // zw rows cross waves for MFMA A-frags
    mfma_gemm_phase(zw, wsm, bias, out, statsOut, redS, redQ, r0, t, lane, wid);
}

// ---------------- K2: BN1+ReLU staging + MFMA GEMM2 + stats2 (128 rows/block) ----------
// Staging loads 16B/lane (uiv4; rows are 128B so 16B-aligned). zw stores remain 4B
// (33-word padded rows break 16B LDS alignment by design).
__global__ __launch_bounds__(512) void gemm128_norm_kernel(
    const bf16_t* __restrict__ in, const float* __restrict__ w, const float* __restrict__ bias,
    const float* __restrict__ statsIn, const float* __restrict__ gIn,
    const float* __restrict__ bIn, bf16_t* __restrict__ out, float* __restrict__ statsOut) {
    __shared__ unsigned zw[128 * 33];
    __shared__ unsigned wsm[64 * 33];
    __shared__ float a1[64], s1[64];
    __shared__ float redS[8][64], redQ[8][64];
    int t = threadIdx.x, lane = t & 63, wid = t >> 6;
    int r0 = blockIdx.x * 128;
    if (t < 64) {
        float mu = statsIn[t] * (1.0f / NN);
        float var = statsIn[64 + t] * (1.0f / NN) - mu * mu;
        float a = gIn[t] * rsqrtf(var + BN_EPS);
        a1[t] = a;
        s1[t] = bIn[t] - mu * a;
    }
    for (int idx = t; idx < 2048; idx += 512) {
        int kk = idx >> 6, c = idx & 63;
        unsigned lo = f2bfbits(w[(2 * kk) * 64 + c]);
        unsigned hi = f2bfbits(w[(2 * kk + 1) * 64 + c]);
        wsm[c * 33 + kk] = lo | (hi << 16);
    }
    __syncthreads();
    for (int idx = t; idx < 1024; idx += 512) {
        int off = idx * 8;       // element offset
        int r = off >> 6;        // row 0..127
        int k = off & 63;        // 0,8,...,56
        uiv4 wv4 = {0u, 0u, 0u, 0u};
        int gr = r0 + r;
        if (gr < NN) wv4 = *(const uiv4*)&in[(size_t)gr * HC + k];
        unsigned* zp = &zw[r * 33 + (k >> 1)];
#pragma unroll
        for (int j = 0; j < 4; ++j) {
            unsigned word = wv4[j];
            int kk = k + 2 * j;
            float v0 = fmaxf(bflo(word) * a1[kk] + s1[kk], 0.f);
            float v1 = fmaxf(bfhi(word) * a1[kk + 1] + s1[kk + 1], 0.f);
            zp[j] = f2bfbits(v0) | (f2bfbits(v1) << 16);
        }
    }
    __syncthreads();
    int l15 = lane & 15, l4 = lane >> 4;
    const unsigned* arow = &zw[(wid * 16 + l15) * 33];
    f32x4 d[4];
#pragma unroll
    for (int tc = 0; tc < 4; ++tc) d[tc] = (f32x4){0.f, 0.f, 0.f, 0.f};
#pragma unroll
    for (int kc = 0; kc < 2; ++kc) {
        int kb = kc * 16 + l4 * 4;
        uint4v aw = {arow[kb], arow[kb + 1], arow[kb + 2], arow[kb + 3]};
        short8v af = __builtin_bit_cast(short8v, aw);
#pragma unroll
        for (int tc = 0; tc < 4; ++tc) {
            const unsigned* brow = &wsm[(tc * 16 + l15) * 33];
            uint4v bw = {brow[kb], brow[kb + 1], brow[kb + 2], brow[kb + 3]};
            d[tc] = __builtin_amdgcn_mfma_f32_16x16x32_bf16(af, __builtin_bit_cast(short8v, bw),
                                                            d[tc], 0, 0, 0);
        }
    }
    float ss[4], qq[4];
#pragma unroll
    for (int tc = 0; tc < 4; ++tc) {
        int cc = tc * 16 + l15;
        float bv = bias[cc];
        float s = 0.f, q = 0.f;
#pragma unroll
        for (int j = 0; j < 4; ++j) {
            int gr = r0 + wid * 16 + l4 * 4 + j;
            if (gr < NN) {
                float v = d[tc][j] + bv;
                out[(size_t)gr * HC + cc] = f2bf(v);
                s += v;
                q += v * v;
            }
        }
        s += __shfl_xor(s, 16); s += __shfl_xor(s, 32);
        q += __shfl_xor(q, 16); q += __shfl_xor(q, 32);
        ss[tc] = s;
        qq[tc] = q;
    }
    if (lane < 16) {
#pragma unroll
        for (int tc = 0; tc < 4; ++tc) {
            redS[wid][tc * 16 + lane] = ss[tc];
            redQ[wid][tc * 16 + lane] = qq[tc];
        }
    }
    __syncthreads();
    if (t < 64) {
        float ts = 0.f, t2 = 0.f;
#pragma unroll
        for (int k = 0; k < 8; ++k) {
            ts += redS[k][t];
            t2 += redQ[k][t];
        }
        atomicAdd(&statsOut[t], ts);
        atomicAdd(&statsOut[64 + t], t2);
    }
}

// ---------------- last-layer gdesc (BN2+ReLU, segmented sum, no h write) ----------------
#define CHK 16
__global__ void gdesc_last_kernel(const bf16_t* __restrict__ u, const float* __restrict__ stats,
                                  const float* __restrict__ g, const float* __restrict__ b,
                                  const int* __restrict__ batch, float* __restrict__ gdesc,
                                  int layer) {
    int lane = threadIdx.x & 63;
    int wid = threadIdx.x >> 6;
    int i0 = (blockIdx.x * 4 + wid) * CHK;
    if (i0 >= NN) return;
    float mu = stats[lane] * (1.0f / NN);
    float var = stats[64 + lane] * (1.0f / NN) - mu * mu;
    float a = g[lane] * rsqrtf(var + BN_EPS);
    float s = b[lane] - mu * a;
    int col = 1 + layer * HC + lane;
    float acc = 0.f;
    int cur = -1;
    int iend = i0 + CHK;
    if (iend > NN) iend = NN;
    for (int i = i0; i < iend; ++i) {
        int gid = batch[i];
        if (gid != cur) {
            if (cur >= 0) atomicAdd(&gdesc[cur * GD_COLS + col], acc);
            cur = gid;
            acc = 0.f;
        }
        acc += fmaxf(bf2f(u[i * HC + lane]) * a + s, 0.f);
    }
    if (cur >= 0) atomicAdd(&gdesc[cur * GD_COLS + col], acc);
}

__global__ void final_gemm_kernel(const float* __restrict__ gdesc, const float* __restrict__ lw,
                                  const float* __restrict__ lb, float* __restrict__ out) {
    int g = blockIdx.x;
    int lane = threadIdx.x;
    float a0 = 0.f, a1 = 0.f;
    for (int j = lane; j < GD_COLS; j += 64) {
        float v = gdesc[g * GD_COLS + j];
        a0 += v * lw[j * 2 + 0];
        a1 += v * lw[j * 2 + 1];
    }
    for (int off = 32; off > 0; off >>= 1) {
        a0 += __shfl_down(a0, off);
        a1 += __shfl_down(a1, off);
    }
    if (lane == 0) {
        out[g * 2 + 0] = a0 + lb[0];
        out[g * 2 + 1] = a1 + lb[1];
    }
}

extern "C" void kernel_launch(void* const* d_in, const int* in_sizes, int n_in, void* d_out,
                              int out_size, void* d_ws, size_t ws_size, hipStream_t stream) {
    const float* x = (const float*)d_in[0];
    const int* ei = (const int*)d_in[1];
    const int* batch = (const int*)d_in[2];
    const float* w1_0 = (const float*)d_in[3];
    const float* w1_rest = (const float*)d_in[4];
    const float* b1 = (const float*)d_in[5];
    const float* gm = (const float*)d_in[6];
    const float* bm = (const float*)d_in[7];
    const float* w2 = (const float*)d_in[8];
    const float* b2 = (const float*)d_in[9];
    const float* go = (const float*)d_in[10];
    const float* bo = (const float*)d_in[11];
    const float* lw = (const float*)d_in[12];
    const float* lb = (const float*)d_in[13];
    float* out = (float*)d_out;

    float* stats = (float*)d_ws;                     // NL*256
    float* gdesc = stats + NL * 256;                 // NG*321
    bf16_t* ybuf = (bf16_t*)(gdesc + (size_t)NG * GD_COLS + 64);  // NN*64 bf16
    bf16_t* ubuf = ybuf + (size_t)NN * HC;           // NN*64 bf16
    int* cnt = (int*)(ubuf + (size_t)NN * HC);       // NN
    unsigned short* ssrc = (unsigned short*)(cnt + NN);  // NN*64 ushort

    hipMemsetAsync(cnt, 0, NN * sizeof(int), stream);

    scatter_kernel<<<2048, 256, 0, stream>>>(ei, cnt, ssrc, stats, gdesc);

    layer0_kernel<<<(NN + 63) / 64, 256, 0, stream>>>(x, cnt, ssrc, w1_0, b1, batch, gdesc, ybuf,
                                                      stats);
    gemm128_norm_kernel<<<(NN + 127) / 128, 512, 0, stream>>>(ybuf, w2, b2, stats, gm, bm, ubuf,
                                                              stats + 128);
    for (int l = 1; l < NL; ++l) {
        float* st1 = stats + l * 256;
        float* st2 = st1 + 128;
        float* stPrev = stats + (l - 1) * 256 + 128;
        gather_gemm_kernel<<<(NN + 63) / 64, 512, 0, stream>>>(
            ubuf, stPrev, go + (l - 1) * HC, bo + (l - 1) * HC, cnt, ssrc,
            w1_rest + (size_t)(l - 1) * HC * HC, b1 + l * HC, batch, gdesc, l - 1, ybuf, st1);
        gemm128_norm_kernel<<<(NN + 127) / 128, 512, 0, stream>>>(
            ybuf, w2 + (size_t)l * HC * HC, b2 + l * HC, st1, gm + l * HC, bm + l * HC, ubuf, st2);
    }
    gdesc_last_kernel<<<(NN + 4 * CHK - 1) / (4 * CHK), 256, 0, stream>>>(
        ubuf, stats + 4 * 256 + 128, go + 4 * HC, bo + 4 * HC, batch, gdesc, 4);
    final_gemm_kernel<<<NG, 64, 0, stream>>>(gdesc, lw, lb, out);
}